// Round 1
// baseline (8293.511 us; speedup 1.0000x reference)
//
#include <hip/hip_runtime.h>
#include <math.h>

#define L 50
#define ML 64
#define VOCAB 32000
#define EMBED 1024
#define HID 1024
#define HH 512
#define TOT (VOCAB+ML)
#define NPART 1002

// workspace layout (float offsets)
#define WS_ENC_GATES 0        // [2][4096]
#define WS_C_ENC     8192     // [2][1024]
#define WS_ENC_OUTS  10240    // [64][1024]
#define WS_COPY_ENC  75776    // [64][1024]
#define WS_H_DEC     141312   // [2][1024]
#define WS_C_DEC     143360   // [2][1024]
#define WS_X_DEC     145408   // [3072]
#define WS_DGATES    148480   // [4096]
#define WS_LOGITS    152576   // [32064]
#define WS_PARTS     184640   // [1002*4] {lmax,sumexp,bestkey,bestidx}

__device__ __forceinline__ float wred_sum(float v){
  #pragma unroll
  for(int o=32;o;o>>=1) v += __shfl_xor(v,o,64);
  return v;
}
__device__ __forceinline__ float wred_max(float v){
  #pragma unroll
  for(int o=32;o;o>>=1) v = fmaxf(v,__shfl_xor(v,o,64));
  return v;
}
__device__ __forceinline__ float sigm(float x){ return 1.0f/(1.0f+__expf(-x)); }
__device__ __forceinline__ float d4(float4 a, float4 b){ return a.x*b.x + a.y*b.y + a.z*b.z + a.w*b.w; }

// ---------------- encoder step: redundant cell-update(t-1) + gates GEMV(t) ----------------
__global__ __launch_bounds__(256) void k_enc_step(
  const int* __restrict__ xt, const float* __restrict__ emb,
  const float* __restrict__ Wih_f, const float* __restrict__ Whh_f,
  const float* __restrict__ bih_f, const float* __restrict__ bhh_f,
  const float* __restrict__ Wih_b, const float* __restrict__ Whh_b,
  const float* __restrict__ bih_b, const float* __restrict__ bhh_b,
  float* __restrict__ ws, int t)
{
  __shared__ __align__(16) float h_lds[1024];   // [hf(512), hb(512)]
  __shared__ __align__(16) float xe[1024];
  const int tid = threadIdx.x;
  float* gates   = ws + WS_ENC_GATES;
  float* c_enc   = ws + WS_C_ENC;
  float* enc_outs= ws + WS_ENC_OUTS;
  {
    const int tok = xt[t];
    const float* er = emb + (size_t)tok*EMBED;
    for(int j=tid;j<1024;j+=256) xe[j]=er[j];
  }
  if(t>0){
    const float* gp = gates + ((t-1)&1)*4096;
    const float* cp = c_enc + (t&1)*1024;        // c_{t-2}
    float* cw = c_enc + ((t-1)&1)*1024;          // c_{t-1}
    for(int u=tid;u<1024;u+=256){
      int base = (u<512)?0:2048;
      int uu   = (u<512)?u:(u-512);
      float ig=gp[base+uu], fg=gp[base+512+uu], gg=gp[base+1024+uu], og=gp[base+1536+uu];
      float cprev = (t==1)?0.0f:cp[u];
      float c = sigm(fg)*cprev + sigm(ig)*tanhf(gg);
      float h = sigm(og)*tanhf(c);
      h_lds[u]=h;
      if(blockIdx.x==0){
        cw[u]=c;
        enc_outs[(size_t)(t-1)*1024+u]=h;
      }
    }
  }
  __syncthreads();
  float* gw = gates + (t&1)*4096;
  const int wave=tid>>6, lane=tid&63;
  for(int rr=0;rr<2;rr++){
    int r = blockIdx.x*8 + wave*2 + rr;          // 0..4095
    bool isF = (r<2048);
    int rl = isF? r : r-2048;
    const float* Wih = isF? Wih_f : Wih_b;
    const float* Whh = isF? Whh_f : Whh_b;
    float bias = isF? (bih_f[rl]+bhh_f[rl]) : (bih_b[rl]+bhh_b[rl]);
    const float* wr = Wih + (size_t)rl*EMBED;
    float acc=0.0f;
    #pragma unroll
    for(int c4=0;c4<4;c4++){
      int m=c4*256+lane*4;
      acc += d4(*(const float4*)(wr+m), *(const float4*)(&xe[m]));
    }
    if(t>0){
      const float* hr = Whh + (size_t)rl*HH;
      const float* hs = &h_lds[isF?0:512];
      #pragma unroll
      for(int c4=0;c4<2;c4++){
        int m=c4*256+lane*4;
        acc += d4(*(const float4*)(hr+m), *(const float4*)(&hs[m]));
      }
    }
    acc = wred_sum(acc);
    if(lane==0) gw[r]=acc+bias;
  }
}

// ---------------- encoder final: h_49,c_49 -> enc_outs[49], h0/c0, states[0], zero pad ----------------
__global__ __launch_bounds__(256) void k_enc_final(float* __restrict__ ws, float* __restrict__ out)
{
  const int tid=threadIdx.x;
  float* gates = ws + WS_ENC_GATES;
  float* c_enc = ws + WS_C_ENC;
  float* enc_outs = ws + WS_ENC_OUTS;
  float* h_dec = ws + WS_H_DEC;
  float* c_dec = ws + WS_C_DEC;
  const float* gp = gates + ((L-1)&1)*4096;  // gates_49
  const float* cp = c_enc + ((L-2)&1)*1024;  // c_48
  for(int u=tid;u<1024;u+=256){
    int base=(u<512)?0:2048;
    int uu=(u<512)?u:(u-512);
    float ig=gp[base+uu], fg=gp[base+512+uu], gg=gp[base+1024+uu], og=gp[base+1536+uu];
    float c = sigm(fg)*cp[u] + sigm(ig)*tanhf(gg);
    float h = sigm(og)*tanhf(c);
    enc_outs[(size_t)(L-1)*1024+u]=h;
    h_dec[1024+u]=h;     // h0 -> buffer 1 (read as h_{-1})
    c_dec[1024+u]=c;     // c0 -> buffer 1
    out[u]=h;            // states[0]
  }
  for(int j=tid;j<(ML-L)*1024;j+=256) enc_outs[(size_t)L*1024+j]=0.0f;
}

// ---------------- copy_enc = tanh(enc_outs @ copy_W^T + copy_b) ----------------
__global__ __launch_bounds__(256) void k_copy_enc(
  const float* __restrict__ copy_W, const float* __restrict__ copy_b, float* __restrict__ ws)
{
  float* enc_outs = ws+WS_ENC_OUTS;
  float* cenc = ws+WS_COPY_ENC;
  const int wave=threadIdx.x>>6, lane=threadIdx.x&63;
  for(int jj=0;jj<4;jj++){
    int j = blockIdx.x*16 + wave*4 + jj;   // 0..1023
    const float* wr = copy_W + (size_t)j*1024;
    float4 w0=*(const float4*)(wr+0*256+lane*4);
    float4 w1=*(const float4*)(wr+1*256+lane*4);
    float4 w2=*(const float4*)(wr+2*256+lane*4);
    float4 w3=*(const float4*)(wr+3*256+lane*4);
    float bj = copy_b[j];
    for(int k=0;k<ML;k++){
      const float* er = enc_outs + (size_t)k*1024;
      float acc = d4(w0,*(const float4*)(er+0*256+lane*4))
                + d4(w1,*(const float4*)(er+1*256+lane*4))
                + d4(w2,*(const float4*)(er+2*256+lane*4))
                + d4(w3,*(const float4*)(er+3*256+lane*4));
      acc = wred_sum(acc);
      if(lane==0) cenc[(size_t)k*1024+j]=tanhf(acc+bj);
    }
  }
}

// ---------------- decoder pre-kernel (1 block): finalize step t-1, prep x_dec for step t ----------------
__global__ __launch_bounds__(256) void k_dec_pre(
  const int* __restrict__ xt, const float* __restrict__ amask,
  const float* __restrict__ emb,
  const float* __restrict__ attn_W, const float* __restrict__ attn_b,
  float* __restrict__ ws, float* __restrict__ out, int t)
{
  __shared__ __align__(16) float dec_in[1024];
  __shared__ __align__(16) float hprev[1024];
  __shared__ float pc[64];
  __shared__ float attw[64];
  __shared__ float r_lm[256], r_sm[256], r_ky[256];
  __shared__ int r_ix[256];
  __shared__ float s_lmax, s_Z;
  __shared__ int s_act;
  const int tid=threadIdx.x;
  float* h_dec=ws+WS_H_DEC; float* x_dec=ws+WS_X_DEC;
  float* logits=ws+WS_LOGITS; float* parts=ws+WS_PARTS;
  float* enc_outs=ws+WS_ENC_OUTS;

  if(t==0){
    for(int j=tid;j<1024;j+=256){
      x_dec[j]=emb[j];          // sos = embedding[0]
      x_dec[1024+j]=0.0f;       // selective = 0 (first)
      x_dec[2048+j]=0.0f;       // attentive = 0 (first)
    }
    return;
  }
  // ---- finalize step t-1: reduce block partials ----
  {
    float lm=-INFINITY, sm=0.0f, ky=-INFINITY; int ix=0x7fffffff;
    for(int i=tid;i<NPART;i+=256){
      const float4 p = *(const float4*)(parts+(size_t)i*4);
      float plm=p.x, psm=p.y, pky=p.z; int pix=__float_as_int(p.w);
      if(plm>lm){ sm = sm*__expf(lm-plm)+psm; lm=plm; }
      else sm += psm*__expf(plm-lm);
      if(pky>ky || (pky==ky && pix<ix)){ ky=pky; ix=pix; }
    }
    r_lm[tid]=lm; r_sm[tid]=sm; r_ky[tid]=ky; r_ix[tid]=ix;
    __syncthreads();
    for(int s=128;s;s>>=1){
      if(tid<s){
        float blm=r_lm[tid+s], bsm=r_sm[tid+s];
        float alm=r_lm[tid], a_sm=r_sm[tid];
        if(blm>alm){ r_sm[tid]=a_sm*__expf(alm-blm)+bsm; r_lm[tid]=blm; }
        else r_sm[tid]=a_sm+bsm*__expf(blm-alm);
        float bky=r_ky[tid+s]; int bix=r_ix[tid+s];
        if(bky>r_ky[tid] || (bky==r_ky[tid] && bix<r_ix[tid])){ r_ky[tid]=bky; r_ix[tid]=bix; }
      }
      __syncthreads();
    }
    if(tid==0){
      float lmax=r_lm[0]; float Z=r_sm[0];
      float bky=r_ky[0];
      int aidx = (bky==-INFINITY)?0:r_ix[0];
      bool isv = aidx<VOCAB;
      int kcl = aidx-VOCAB; kcl = kcl<0?0:(kcl>(L-1)?(L-1):kcl);
      int sp = xt[kcl];                 // kcl in [0,49] -> sent_pad = x_tokens
      int action = isv? aidx : sp;
      float prob = amask[aidx]*__expf(logits[aidx]-lmax)/Z;
      if(!isv){
        int a2 = action<0?0:(action>(VOCAB-1)?(VOCAB-1):action);
        prob += amask[a2]*__expf(logits[a2]-lmax)/Z;
      }
      out[65*1024 + (t-1)] = prob;
      out[65*1024 + 64 + (t-1)] = (float)action;
      s_lmax=lmax; s_Z=Z; s_act=action;
    }
  }
  __syncthreads();
  if(t==ML) return;   // nothing more after last step

  const int action = s_act;
  // pc = normalize(mask * probs[VOCAB:])
  if(tid<64){
    int k=tid;
    float v=__expf(logits[VOCAB+k]-s_lmax)/s_Z;
    int sp=(k<L)? xt[k] : -1;
    float m=(k>=1 && k<(L-1) && sp!=action)?1.0f:0.0f;
    float pv=v*m;
    float s=wred_sum(pv);
    pc[k]=(s>0.0f)? pv/s : pv;
  }
  {
    int row = action<0 ? action+VOCAB : action;  // jnp negative-index wrap
    const float* er = emb + (size_t)row*EMBED;
    const float* hp = h_dec + ((t-1)&1)*1024;
    for(int j=tid;j<1024;j+=256){ dec_in[j]=er[j]; hprev[j]=hp[j]; }
  }
  __syncthreads();
  // attention logits (64 rows x 2048)
  const int wave=tid>>6, lane=tid&63;
  for(int rr=0;rr<16;rr++){
    int r=wave*16+rr;
    const float* wr = attn_W + (size_t)r*2048;
    float acc=0.0f;
    #pragma unroll
    for(int c4=0;c4<4;c4++){
      int m=c4*256+lane*4;
      acc += d4(*(const float4*)(wr+m),      *(const float4*)(&dec_in[m]));
      acc += d4(*(const float4*)(wr+1024+m), *(const float4*)(&hprev[m]));
    }
    acc=wred_sum(acc);
    if(lane==0) attw[r]=acc+attn_b[r];
  }
  __syncthreads();
  if(tid<64){
    float v=attw[tid];
    float mx=wred_max(v);
    float e=__expf(v-mx);
    float s=wred_sum(e);
    attw[tid]=e/s;
  }
  __syncthreads();
  // attentive / selective + write x_dec = [dec_in, selective, attentive]
  for(int j=tid;j<1024;j+=256){
    float aA=0.0f,aS=0.0f;
    for(int k=0;k<ML;k++){
      float e=enc_outs[(size_t)k*1024+j];
      aA += attw[k]*e;
      aS += pc[k]*e;
    }
    x_dec[j]=dec_in[j];
    x_dec[1024+j]=aS;
    x_dec[2048+j]=aA;
  }
}

// ---------------- decoder gates GEMV: 4096 x (3072 + 1024) ----------------
__global__ __launch_bounds__(256) void k_dec_gates(
  const float* __restrict__ Wih_d, const float* __restrict__ Whh_d,
  const float* __restrict__ bih_d, const float* __restrict__ bhh_d,
  float* __restrict__ ws, int t)
{
  __shared__ __align__(16) float x_lds[4096];
  const int tid=threadIdx.x;
  float* x_dec=ws+WS_X_DEC; float* h_dec=ws+WS_H_DEC; float* dg=ws+WS_DGATES;
  for(int j=tid;j<3072;j+=256) x_lds[j]=x_dec[j];
  {
    const float* hp=h_dec+((t+1)&1)*1024;   // h_{t-1}
    for(int j=tid;j<1024;j+=256) x_lds[3072+j]=hp[j];
  }
  __syncthreads();
  const int wave=tid>>6, lane=tid&63;
  for(int rr=0;rr<2;rr++){
    int r=blockIdx.x*8+wave*2+rr;
    const float* wr=Wih_d+(size_t)r*3072;
    float acc=0.0f;
    #pragma unroll
    for(int c4=0;c4<12;c4++){
      int m=c4*256+lane*4;
      acc += d4(*(const float4*)(wr+m), *(const float4*)(&x_lds[m]));
    }
    const float* hr=Whh_d+(size_t)r*1024;
    #pragma unroll
    for(int c4=0;c4<4;c4++){
      int m=c4*256+lane*4;
      acc += d4(*(const float4*)(hr+m), *(const float4*)(&x_lds[3072+m]));
    }
    acc=wred_sum(acc);
    if(lane==0) dg[r]=acc+bih_d[r]+bhh_d[r];
  }
}

// ---------------- decoder gen: redundant cell update + gen/copy GEMV + softmax partials ----------------
__global__ __launch_bounds__(256) void k_dec_gen(
  const float* __restrict__ gen_W, const float* __restrict__ gen_b,
  const float* __restrict__ amask,
  float* __restrict__ ws, float* __restrict__ out, int t)
{
  __shared__ __align__(16) float h_lds[1024];
  __shared__ float w_lm[4], w_sm[4], w_ky[4];
  __shared__ int w_ix[4];
  const int tid=threadIdx.x;
  float* dg=ws+WS_DGATES;
  float* c_dec=ws+WS_C_DEC; float* h_dec=ws+WS_H_DEC;
  float* logits=ws+WS_LOGITS; float* parts=ws+WS_PARTS;
  float* cenc=ws+WS_COPY_ENC;
  {
    const float* cp=c_dec+((t+1)&1)*1024;   // c_{t-1}
    float* cw=c_dec+(t&1)*1024;
    float* hw=h_dec+(t&1)*1024;
    for(int u=tid;u<1024;u+=256){
      float ig=dg[u], fg=dg[1024+u], gg=dg[2048+u], og=dg[3072+u];
      float c=sigm(fg)*cp[u]+sigm(ig)*tanhf(gg);
      float h=sigm(og)*tanhf(c);
      h_lds[u]=h;
      if(blockIdx.x==0){ cw[u]=c; hw[u]=h; out[(size_t)(t+1)*1024+u]=h; }  // states[t+1]
    }
  }
  __syncthreads();
  const int wave=tid>>6, lane=tid&63;
  float l8[8];
  int gbase;
  if(blockIdx.x<1000){
    int r0=blockIdx.x*32+wave*8;
    gbase=r0;
    #pragma unroll
    for(int rr=0;rr<8;rr++){
      const float* wr=gen_W+(size_t)(r0+rr)*1024;
      float acc=0.0f;
      #pragma unroll
      for(int c4=0;c4<4;c4++){
        int m=c4*256+lane*4;
        acc += d4(*(const float4*)(wr+m), *(const float4*)(&h_lds[m]));
      }
      acc=wred_sum(acc);
      l8[rr]=acc+gen_b[r0+rr];
    }
  } else {
    int k0=(blockIdx.x-1000)*32+wave*8;
    gbase=VOCAB+k0;
    #pragma unroll
    for(int rr=0;rr<8;rr++){
      const float* wr=cenc+(size_t)(k0+rr)*1024;
      float acc=0.0f;
      #pragma unroll
      for(int c4=0;c4<4;c4++){
        int m=c4*256+lane*4;
        acc += d4(*(const float4*)(wr+m), *(const float4*)(&h_lds[m]));
      }
      acc=wred_sum(acc);
      l8[rr]=acc;
    }
  }
  if(lane==0){
    float lm=-INFINITY, ky=-INFINITY; int ix=0;
    #pragma unroll
    for(int rr=0;rr<8;rr++){
      logits[gbase+rr]=l8[rr];
      lm=fmaxf(lm,l8[rr]);
      float mk=amask[gbase+rr];
      float kk = (mk>0.0f)? (l8[rr]+__logf(mk)) : -INFINITY;
      if(kk>ky){ ky=kk; ix=gbase+rr; }   // strict > keeps first index on ties
    }
    float sm=0.0f;
    #pragma unroll
    for(int rr=0;rr<8;rr++) sm += __expf(l8[rr]-lm);
    w_lm[wave]=lm; w_sm[wave]=sm; w_ky[wave]=ky; w_ix[wave]=ix;
  }
  __syncthreads();
  if(tid==0){
    float lm=w_lm[0], sm=w_sm[0], ky=w_ky[0]; int ix=w_ix[0];
    for(int w=1;w<4;w++){
      float blm=w_lm[w], bsm=w_sm[w];
      if(blm>lm){ sm=sm*__expf(lm-blm)+bsm; lm=blm; }
      else sm += bsm*__expf(blm-lm);
      if(w_ky[w]>ky || (w_ky[w]==ky && w_ix[w]<ix)){ ky=w_ky[w]; ix=w_ix[w]; }
    }
    float4 p; p.x=lm; p.y=sm; p.z=ky; p.w=__int_as_float(ix);
    *(float4*)(parts+(size_t)blockIdx.x*4)=p;
  }
}

extern "C" void kernel_launch(void* const* d_in, const int* in_sizes, int n_in,
                              void* d_out, int out_size, void* d_ws, size_t ws_size,
                              hipStream_t stream)
{
  const int*   xt     = (const int*)d_in[0];
  const float* amask  = (const float*)d_in[1];
  const float* emb    = (const float*)d_in[2];
  const float* Wih_f  = (const float*)d_in[3];
  const float* Whh_f  = (const float*)d_in[4];
  const float* bih_f  = (const float*)d_in[5];
  const float* bhh_f  = (const float*)d_in[6];
  const float* Wih_b  = (const float*)d_in[7];
  const float* Whh_b  = (const float*)d_in[8];
  const float* bih_b  = (const float*)d_in[9];
  const float* bhh_b  = (const float*)d_in[10];
  const float* Wih_d  = (const float*)d_in[11];
  const float* Whh_d  = (const float*)d_in[12];
  const float* bih_d  = (const float*)d_in[13];
  const float* bhh_d  = (const float*)d_in[14];
  const float* attn_W = (const float*)d_in[15];
  const float* attn_b = (const float*)d_in[16];
  const float* gen_W  = (const float*)d_in[17];
  const float* gen_b  = (const float*)d_in[18];
  const float* copy_W = (const float*)d_in[19];
  const float* copy_b = (const float*)d_in[20];
  float* out=(float*)d_out;
  float* ws =(float*)d_ws;   // needs ~755 KB

  for(int t=0;t<L;t++)
    k_enc_step<<<512,256,0,stream>>>(xt,emb,Wih_f,Whh_f,bih_f,bhh_f,Wih_b,Whh_b,bih_b,bhh_b,ws,t);
  k_enc_final<<<1,256,0,stream>>>(ws,out);
  k_copy_enc<<<64,256,0,stream>>>(copy_W,copy_b,ws);
  for(int t=0;t<ML;t++){
    k_dec_pre  <<<1,256,0,stream>>>(xt,amask,emb,attn_W,attn_b,ws,out,t);
    k_dec_gates<<<512,256,0,stream>>>(Wih_d,Whh_d,bih_d,bhh_d,ws,t);
    k_dec_gen  <<<NPART,256,0,stream>>>(gen_W,gen_b,amask,ws,out,t);
  }
  k_dec_pre<<<1,256,0,stream>>>(xt,amask,emb,attn_W,attn_b,ws,out,ML);
}